// Round 3
// baseline (634.300 us; speedup 1.0000x reference)
//
#include <hip/hip_runtime.h>
#include <math.h>

#define BB 4
#define SS 8192
#define HH 16
#define DD 64
#define ROT 32
#define NG (BB * SS * HH)   // 524288 rows of 64
#define TILES (NG / DD)     // 8192 tiles (64 rows each)
#define TPB 4               // tiles per (single-wave) block
#define GRID (TILES / TPB)  // 2048 blocks -> 8 waves/CU, all resident
#define LSTR 68             // LDS row stride (dwords): 272 B, 16B-aligned, bank-spread

// ---------------------------------------------------------------------------
// Setup: G_comb (column-op composition, row-parallel) then M = G @ matrix.
// One block, 256 threads. i==j edge: the .at[] chain leaves G[i,i]=sin.
// ---------------------------------------------------------------------------
__global__ void setup_M(const float* __restrict__ matrix,
                        const float* __restrict__ thetas,
                        const float* __restrict__ tscale,
                        const int* __restrict__ pairs, float* __restrict__ M) {
  __shared__ float G[DD * DD];
  const int t = threadIdx.x;  // 256
  for (int i = t; i < DD * DD; i += 256) G[i] = ((i / DD) == (i % DD)) ? 1.f : 0.f;
  __syncthreads();
  if (t < DD) {  // thread t owns row t; acc@G touches cols i,j only
    const float ts = tscale[0];
    for (int r = 0; r < ROT; ++r) {
      const int i = pairs[2 * r], j = pairs[2 * r + 1];
      const float th = thetas[r] * ts;
      const float cc = cosf(th), sn = sinf(th);
      if (i == j) {
        G[t * DD + i] *= sn;
      } else {
        const float a = G[t * DD + i], b = G[t * DD + j];
        G[t * DD + i] = a * cc + b * sn;
        G[t * DD + j] = b * cc - a * sn;
      }
    }
  }
  __syncthreads();
  for (int e = t; e < DD * DD; e += 256) {  // 16 elems/thread
    const int row = e >> 6, col = e & 63;
    float s = 0.f;
    for (int k = 0; k < DD; ++k) s = fmaf(G[row * DD + k], matrix[k * DD + col], s);
    M[e] = s;
  }
}

// cos/sin table PRESCALED by 32 (= sqrt(1024)); radians via sinf/cosf to match
// the reference's fp32 rounding. tab[s*64+d]=32cos(s*invf[d]); +32 -> sin.
__global__ void setup_table(const float* __restrict__ invf,
                            float* __restrict__ tab) {
  const int idx = blockIdx.x * 256 + threadIdx.x;
  if (idx >= SS * 32) return;
  const int s = idx >> 5, d = idx & 31;
  const float ang = (float)s * invf[d];
  tab[s * 64 + d] = 32.0f * cosf(ang);
  tab[s * 64 + 32 + d] = 32.0f * sinf(ang);
}

// ---------------------------------------------------------------------------
// Main: one wave per block, zero barriers. Lane l owns row l of a 64-row tile.
// stage(regs->LDS) -> issue next tile's loads -> matvec (M in SGPRs, acc[64])
// -> RoPE epilogue (chunked) -> overwrite own LDS row -> coalesced stores.
// All cross-lane LDS deps are intra-wave: in-order DS pipe + lgkmcnt waits.
// ---------------------------------------------------------------------------
__global__ __launch_bounds__(64, 2) void apply_rot(
    const float* __restrict__ x, const float* __restrict__ M,
    const float* __restrict__ tab, const float* __restrict__ invf,
    float* __restrict__ out) {
  __shared__ float buf[DD * LSTR];  // 17408 B -> 9 waves/CU max
  const int l = threadIdx.x;        // 0..63
  const int tile0 = blockIdx.x * TPB;
  const int rbase = l >> 4, c4 = l & 15;

  float4 st[16];
  {  // prologue: issue tile0 loads (coalesced: lane l -> f4 j*64+l)
    const float4* __restrict__ xg = (const float4*)x + (size_t)tile0 * DD * 16;
#pragma unroll
    for (int j = 0; j < 16; ++j) st[j] = xg[j * 64 + l];
  }

  for (int t = 0; t < TPB; ++t) {
    const int tile = tile0 + t;

    // stage tile t: lane l holds f4 (row 4j+rbase, col4 c4)
#pragma unroll
    for (int j = 0; j < 16; ++j)
      *(float4*)&buf[(4 * j + rbase) * LSTR + c4 * 4] = st[j];

    // issue async prefetch of tile t+1 (flies under the whole compute phase)
    if (t + 1 < TPB) {
      const float4* __restrict__ xg =
          (const float4*)x + (size_t)(tile + 1) * DD * 16;
#pragma unroll
      for (int j = 0; j < 16; ++j) st[j] = xg[j * 64 + l];
    }

    // matvec: row l x M(64x64); M index wave-uniform -> SGPR operands
    float acc[DD];
#pragma unroll
    for (int c = 0; c < DD; ++c) acc[c] = 0.f;
    const float* __restrict__ xr = &buf[l * LSTR];
#pragma unroll
    for (int k4 = 0; k4 < 16; ++k4) {
      const float4 xv = *(const float4*)&xr[k4 * 4];
      const float* __restrict__ m = M + k4 * 4 * DD;
#pragma unroll
      for (int c = 0; c < DD; ++c) acc[c] = fmaf(xv.x, m[c], acc[c]);
#pragma unroll
      for (int c = 0; c < DD; ++c) acc[c] = fmaf(xv.y, m[DD + c], acc[c]);
#pragma unroll
      for (int c = 0; c < DD; ++c) acc[c] = fmaf(xv.z, m[2 * DD + c], acc[c]);
#pragma unroll
      for (int c = 0; c < DD; ++c) acc[c] = fmaf(xv.w, m[3 * DD + c], acc[c]);
    }

    // RoPE epilogue, 4 chunks of 8 pairs; overwrite own LDS row
    const int spos = (int)(((size_t)tile * DD + l) >> 4) & (SS - 1);
    const float* __restrict__ tb = tab + (size_t)spos * 64;
    float* __restrict__ orow = &buf[l * LSTR];
#pragma unroll
    for (int q = 0; q < 4; ++q) {
      float cz[8], sz[8];
      if (tab) {
#pragma unroll
        for (int i = 0; i < 8; ++i) {
          cz[i] = tb[8 * q + i];
          sz[i] = tb[32 + 8 * q + i];
        }
      } else {  // fallback if ws too small: same fp32 formula as reference
#pragma unroll
        for (int i = 0; i < 8; ++i) {
          const float ang = (float)spos * invf[8 * q + i];
          cz[i] = 32.0f * cosf(ang);
          sz[i] = 32.0f * sinf(ang);
        }
      }
#pragma unroll
      for (int i = 0; i < 8; ++i) {
        const int d = 8 * q + i;
        const float e = acc[2 * d], o = acc[2 * d + 1];
        orow[d] = e * cz[i] - o * sz[i];        // lo half (col d)
        orow[32 + d] = e * sz[i] + o * cz[i];   // hi half (col 32+d)
      }
    }

    // coalesced stores (fire-and-forget)
    float4* __restrict__ og = (float4*)out + (size_t)tile * DD * 16;
#pragma unroll
    for (int j = 0; j < 16; ++j)
      og[j * 64 + l] = *(const float4*)&buf[(4 * j + rbase) * LSTR + c4 * 4];
  }
}

// ---------------------------------------------------------------------------
extern "C" void kernel_launch(void* const* d_in, const int* in_sizes, int n_in,
                              void* d_out, int out_size, void* d_ws,
                              size_t ws_size, hipStream_t stream) {
  const float* x = (const float*)d_in[0];       // (4, 8192, 1024) f32
  const float* matrix = (const float*)d_in[1];  // (64, 64) f32
  const float* thetas = (const float*)d_in[2];  // (32,) f32
  const float* tscale = (const float*)d_in[3];  // (1,) f32
  const float* invf = (const float*)d_in[4];    // (32,) f32
  const int* pairs = (const int*)d_in[5];       // (32, 2) i32
  float* out = (float*)d_out;

  float* M = (float*)d_ws;   // 4096 f
  float* tab = M + DD * DD;  // SS*64 f = 2 MB
  const size_t need = (size_t)(DD * DD + SS * 64) * sizeof(float);
  const bool have_tab = ws_size >= need;

  setup_M<<<1, 256, 0, stream>>>(matrix, thetas, tscale, pairs, M);
  if (have_tab) setup_table<<<(SS * 32) / 256, 256, 0, stream>>>(invf, tab);
  apply_rot<<<GRID, 64, 0, stream>>>(x, M, have_tab ? tab : nullptr, invf, out);
}